// Round 9
// baseline (250.779 us; speedup 1.0000x reference)
//
#include <hip/hip_runtime.h>
#include <hip/hip_bf16.h>

// Problem constants (B=2, T=2048, C=1024, NH=16, NKV=8, HD=64, Q_PER_KV=2)
#define BB 2
#define TT 2048
#define CC 1024
#define NH 16
#define NKV 8
#define HD 64

typedef __attribute__((ext_vector_type(8))) short short8;   // 8 bf16 (MFMA A/B frag)
typedef __attribute__((ext_vector_type(4))) float float4v;  // MFMA C/D frag

__device__ __forceinline__ ushort f2bf(float f) {
    __hip_bfloat16 h = __float2bfloat16(f);
    union { __hip_bfloat16 h; ushort u; } v; v.h = h; return v.u;
}

// async global->LDS, 16B per lane; lptr must be wave-uniform, HW adds lane*16
__device__ __forceinline__ void gload16(const ushort* g, ushort* l) {
    __builtin_amdgcn_global_load_lds(
        (const __attribute__((address_space(1))) unsigned int*)g,
        (__attribute__((address_space(3))) unsigned int*)l, 16, 0, 0);
}

// ---------------------------------------------------------------------------
// Fused prep: x f32->bf16 conv (blocks 0..4095) + weight transposes
// (f32 [K][N] -> bf16 [N][K], 64x64 LDS tiles). One launch instead of 5.
// ---------------------------------------------------------------------------
__device__ __forceinline__ void transpose_tile(
    const float* __restrict__ src, ushort* __restrict__ dst,
    int Kd, int Nd, int kt, int nt, float* tile /*[64][65]*/)
{
    const int tid = threadIdx.x;
    {
        int r = tid >> 2, c = (tid & 3) * 16;
        #pragma unroll
        for (int i = 0; i < 4; i++) {
            float4 v = *(const float4*)&src[(size_t)(kt + r) * Nd + nt + c + i * 4];
            tile[r * 65 + c + i * 4 + 0] = v.x;
            tile[r * 65 + c + i * 4 + 1] = v.y;
            tile[r * 65 + c + i * 4 + 2] = v.z;
            tile[r * 65 + c + i * 4 + 3] = v.w;
        }
    }
    __syncthreads();
    {
        int n = tid >> 2, k = (tid & 3) * 16;
        #pragma unroll
        for (int i = 0; i < 2; i++) {
            ushort u[8];
            #pragma unroll
            for (int j = 0; j < 8; j++) u[j] = f2bf(tile[(k + i * 8 + j) * 65 + n]);
            *(uint4*)&dst[(size_t)(nt + n) * Kd + kt + k + i * 8] = *(uint4*)u;
        }
    }
}

__global__ __launch_bounds__(256) void prep_kernel(
    const float* __restrict__ x, ushort* __restrict__ xb,
    const float* __restrict__ Wq, const float* __restrict__ Wk,
    const float* __restrict__ Wv, const float* __restrict__ Wproj,
    ushort* __restrict__ WqkvT, ushort* __restrict__ WpT)
{
    __shared__ float tile[64 * 65];
    const int bid = blockIdx.x;
    if (bid < 4096) {
        int i = (bid * 256 + threadIdx.x) * 4;
        float4 v = *(const float4*)&x[i];
        xb[i + 0] = f2bf(v.x);
        xb[i + 1] = f2bf(v.y);
        xb[i + 2] = f2bf(v.z);
        xb[i + 3] = f2bf(v.w);
        return;
    }
    int t = bid - 4096;
    if (t < 256) {
        transpose_tile(Wq, WqkvT, 1024, 1024, (t >> 4) * 64, (t & 15) * 64, tile);
    } else if (t < 384) {
        t -= 256;
        transpose_tile(Wk, WqkvT + (size_t)1024 * 1024, 1024, 512, (t >> 3) * 64, (t & 7) * 64, tile);
    } else if (t < 512) {
        t -= 384;
        transpose_tile(Wv, WqkvT + (size_t)1536 * 1024, 1024, 512, (t >> 3) * 64, (t & 7) * 64, tile);
    } else {
        t -= 512;
        transpose_tile(Wproj, WpT, 1024, 1024, (t >> 4) * 64, (t & 15) * 64, tile);
    }
}

// ---------------------------------------------------------------------------
// bf16 GEMM (m97 structure): C = A @ Bt^T. A[M][K], Bt[N][K] row-major bf16,
// C f32. Tile BMx128, BK=32, 4 waves; global_load_lds staging, no conflicts.
// ---------------------------------------------------------------------------
template<int BM>
__global__ __launch_bounds__(256) void gemm_bt_kernel(
    const ushort* __restrict__ A, const ushort* __restrict__ Bt,
    float* __restrict__ Cp, int M, int N, int K, int ldc)
{
    constexpr int RT = BM / 32;
    __shared__ ushort As[BM][32];
    __shared__ ushort Bs[128][32];

    const int m0 = blockIdx.x * BM;
    const int n0 = blockIdx.y * 128;
    const int tid = threadIdx.x;
    const int lane = tid & 63;
    const int w = tid >> 6;
    const int lr = lane & 15, lc = lane >> 4;
    const int wm = (w >> 1) * (BM / 2), wn = (w & 1) * 64;

    float4v acc[RT][4] = {};

    for (int k0 = 0; k0 < K; k0 += 32) {
        #pragma unroll
        for (int s = 0; s < BM / 64; s++) {
            int rb = w * (BM / 4) + s * 16;
            gload16(&A[(size_t)(m0 + rb + (lane >> 2)) * K + k0 + (lane & 3) * 8], &As[rb][0]);
        }
        #pragma unroll
        for (int s = 0; s < 2; s++) {
            int rb = w * 32 + s * 16;
            gload16(&Bt[(size_t)(n0 + rb + (lane >> 2)) * K + k0 + (lane & 3) * 8], &Bs[rb][0]);
        }
        __syncthreads();

        short8 af[RT], bf[4];
        #pragma unroll
        for (int t = 0; t < RT; t++)
            af[t] = *(const short8*)&As[wm + t * 16 + lr][lc * 8];
        #pragma unroll
        for (int t = 0; t < 4; t++)
            bf[t] = *(const short8*)&Bs[wn + t * 16 + lr][lc * 8];
        #pragma unroll
        for (int rt = 0; rt < RT; rt++)
            #pragma unroll
            for (int ct = 0; ct < 4; ct++)
                acc[rt][ct] = __builtin_amdgcn_mfma_f32_16x16x32_bf16(af[rt], bf[ct], acc[rt][ct], 0, 0, 0);
        __syncthreads();
    }

    #pragma unroll
    for (int rt = 0; rt < RT; rt++)
        #pragma unroll
        for (int ct = 0; ct < 4; ct++)
            #pragma unroll
            for (int r = 0; r < 4; r++) {
                int row = m0 + wm + rt * 16 + lc * 4 + r;
                int col = n0 + wn + ct * 16 + lr;
                Cp[(size_t)row * ldc + col] = acc[rt][ct][r];
            }
}

// ---------------------------------------------------------------------------
// Per-(b,t): gate + ve-add, RoPE + RMSNorm. qkv row = [q(1024)|k(512)|v(512)] f32.
// Writes Q (B,NH,T,HD), K (B,NKV,T,HD), V natural (B,NKV,T,HD) — all coalesced.
// ---------------------------------------------------------------------------
__global__ __launch_bounds__(256) void qkv_post_kernel(
    const float* __restrict__ qkv, const float* __restrict__ x,
    const float* __restrict__ ve, const float* __restrict__ cosb,
    const float* __restrict__ sinb, const float* __restrict__ wgate,
    ushort* __restrict__ Qb, ushort* __restrict__ Kb, ushort* __restrict__ Vn)
{
    const int bt = blockIdx.x;
    const int b = bt >> 11, t = bt & 2047;
    const int tid = threadIdx.x;
    const int lane = tid & 63;
    const int w = tid >> 6;
    __shared__ float gateS[8];

    {
        int g = tid >> 5, i = tid & 31;
        float p = x[(size_t)bt * CC + i] * wgate[i * 8 + g];
        #pragma unroll
        for (int off = 16; off; off >>= 1) p += __shfl_down(p, off, 32);
        if (i == 0) gateS[g] = 2.f / (1.f + __expf(-p));
    }
    __syncthreads();

    const float c = cosb[t * 32 + (lane & 31)];
    const float s = sinb[t * 32 + (lane & 31)];
    for (int hh = w; hh < 24; hh += 4) {
        const float* z = &qkv[(size_t)bt * 2048 + hh * 64];
        float v = z[lane];
        float other = __shfl_xor(v, 32);
        float x1 = (lane < 32) ? v : other;
        float x2 = (lane < 32) ? other : v;
        float val = (lane < 32) ? (x1 * c + x2 * s) : (-x1 * s + x2 * c);
        float ss = val * val;
        #pragma unroll
        for (int off = 32; off; off >>= 1) ss += __shfl_xor(ss, off);
        float scale = rsqrtf(ss * (1.f / 64.f) + 1.1920929e-07f);
        ushort ob = f2bf(val * scale);
        if (hh < 16) Qb[(((size_t)b * NH + hh) * TT + t) * HD + lane] = ob;
        else         Kb[(((size_t)b * NKV + (hh - 16)) * TT + t) * HD + lane] = ob;
    }

    for (int e = tid; e < NKV * HD; e += 256) {
        int kh = e >> 6, d = e & 63;
        float v = qkv[(size_t)bt * 2048 + 1536 + e] + gateS[kh] * ve[(size_t)bt * 512 + e];
        Vn[(((size_t)b * NKV + kh) * TT + t) * HD + d] = f2bf(v);
    }
}

// ---------------------------------------------------------------------------
// V natural (B,NKV,T,HD) -> V^T (B,NKV,HD,T): LDS-tiled, coalesced both ways.
// ---------------------------------------------------------------------------
__global__ __launch_bounds__(256) void v_transpose_kernel(
    const ushort* __restrict__ Vn, ushort* __restrict__ Vt)
{
    __shared__ ushort tile[64][72];
    const int t0 = blockIdx.x * 64;
    const int bh = blockIdx.y;
    const ushort* src = &Vn[(size_t)bh * TT * HD + (size_t)t0 * HD];
    ushort* dst = &Vt[(size_t)bh * HD * TT + t0];
    const int tid = threadIdx.x;
    {
        int r = tid >> 2, c = (tid & 3) * 16;
        #pragma unroll
        for (int i = 0; i < 2; i++)
            *(uint4*)&tile[r][c + i * 8] = *(const uint4*)&src[(size_t)r * HD + c + i * 8];
    }
    __syncthreads();
    {
        int d = tid >> 2, c = (tid & 3) * 16;
        #pragma unroll
        for (int i = 0; i < 2; i++) {
            ushort u[8];
            #pragma unroll
            for (int j = 0; j < 8; j++) u[j] = tile[c + i * 8 + j][d];
            *(uint4*)&dst[(size_t)d * TT + c + i * 8] = *(uint4*)u;
        }
    }
}

// ---------------------------------------------------------------------------
// Split-KV flash attention, 8 waves/block striping key tiles (chain 8->4),
// unnormalized exp (q,k RMS-normed -> f32-safe), exact-sum merge over 8
// partials. XCD-aware block mapping: xcd = gid&7 sees only 2 (b,kvh) combos.
// ---------------------------------------------------------------------------
__global__ __launch_bounds__(512) void attn_kernel(
    const ushort* __restrict__ Qb, const ushort* __restrict__ Kb,
    const ushort* __restrict__ Vt, ushort* __restrict__ Yb,
    const int* __restrict__ winp)
{
    // XCD-grouped, heavy-first mapping (2048 blocks)
    const int gid = blockIdx.x;
    const int xcd = gid & 7;
    const int slot = gid >> 3;          // 256 slots per xcd
    const int csel = slot >> 7;         // 2 (b,kvh) combos per xcd
    const int rest = slot & 127;
    const int combo = xcd + csel * 8;   // 0..15
    const int b = combo >> 3;
    const int kvh = combo & 7;
    const int h = kvh * 2 + (rest >> 6);
    const int qw = 63 - (rest & 63);    // heavy-first

    const int q0 = qw * 32;
    const bool local = (h >= 8);
    int window = *winp;
    if (window < 0 || window > TT) window = TT;
    const int tid = threadIdx.x;
    const int w = tid >> 6;             // 0..7
    const int lane = tid & 63;
    const int lr = lane & 15, lc = lane >> 4;

    __shared__ ushort Ps[8][16][72];    // per-wave P^T scratch
    __shared__ float4v Ol[8][4][64];    // per-wave O^T partials (one rt phase)
    __shared__ float Ll[8][16];         // per-wave row sums (one rt phase)

    const ushort* qbase = &Qb[(((size_t)b * NH + h) * TT + q0) * HD];
    short8 qf[2][2];
    #pragma unroll
    for (int rt = 0; rt < 2; rt++)
        #pragma unroll
        for (int xh = 0; xh < 2; xh++)
            qf[rt][xh] = *(const short8*)&qbase[(size_t)(rt * 16 + lr) * HD + xh * 32 + lc * 8];

    float4v o[2][4] = {};
    float l_[2] = {0.f, 0.f};

    const ushort* Kbase = &Kb[((size_t)b * NKV + kvh) * TT * HD];
    const ushort* Vbase = &Vt[((size_t)b * NKV + kvh) * HD * TT];

    const int qlast = q0 + 31;
    int jstart = 0;
    if (local) { int js = q0 - window; if (js > 0) jstart = js & ~63; }
    const int j0first = jstart + w * 64;    // wave's first key tile (stride 512)

    short8 kf[4][2];
    if (j0first <= qlast) {
        #pragma unroll
        for (int jt = 0; jt < 4; jt++) {
            const ushort* kp = &Kbase[(size_t)(j0first + jt * 16 + lr) * HD + lc * 8];
            kf[jt][0] = *(const short8*)kp;
            kf[jt][1] = *(const short8*)(kp + 32);
        }
    }

    for (int j0 = j0first; j0 <= qlast; j0 += 512) {
        short8 vf[4][2];
        #pragma unroll
        for (int ct = 0; ct < 4; ct++) {
            const ushort* vp = &Vbase[(size_t)(ct * 16 + lr) * TT + j0 + lc * 8];
            vf[ct][0] = *(const short8*)vp;
            vf[ct][1] = *(const short8*)(vp + 32);
        }
        short8 kn[4][2];
        const bool more = (j0 + 512 <= qlast);
        if (more) {
            #pragma unroll
            for (int jt = 0; jt < 4; jt++) {
                const ushort* kp = &Kbase[(size_t)(j0 + 512 + jt * 16 + lr) * HD + lc * 8];
                kn[jt][0] = *(const short8*)kp;
                kn[jt][1] = *(const short8*)(kp + 32);
            }
        }

        float4v st[2][4];
        #pragma unroll
        for (int jt = 0; jt < 4; jt++)
            #pragma unroll
            for (int rt = 0; rt < 2; rt++) {
                float4v z = {};
                z = __builtin_amdgcn_mfma_f32_16x16x32_bf16(kf[jt][0], qf[rt][0], z, 0, 0, 0);
                z = __builtin_amdgcn_mfma_f32_16x16x32_bf16(kf[jt][1], qf[rt][1], z, 0, 0, 0);
                st[rt][jt] = z;
            }

        const bool need_c = (j0 + 63 > q0);
        const bool need_w = local && (j0 < qlast - window);

        #pragma unroll
        for (int rt = 0; rt < 2; rt++) {
            const int qrow = q0 + rt * 16 + lr;
            float p[4][4];
            if (need_c || need_w) {
                #pragma unroll
                for (int jt = 0; jt < 4; jt++)
                    #pragma unroll
                    for (int r = 0; r < 4; r++) {
                        int key = j0 + jt * 16 + lc * 4 + r;
                        bool ok = (key <= qrow) && (!local || key >= qrow - window);
                        p[jt][r] = ok ? __expf(st[rt][jt][r] * 0.125f) : 0.f;
                    }
            } else {
                #pragma unroll
                for (int jt = 0; jt < 4; jt++)
                    #pragma unroll
                    for (int r = 0; r < 4; r++)
                        p[jt][r] = __expf(st[rt][jt][r] * 0.125f);
            }
            float s0 = (p[0][0] + p[0][1]) + (p[0][2] + p[0][3]);
            float s1 = (p[1][0] + p[1][1]) + (p[1][2] + p[1][3]);
            float s2 = (p[2][0] + p[2][1]) + (p[2][2] + p[2][3]);
            float s3 = (p[3][0] + p[3][1]) + (p[3][2] + p[3][3]);
            l_[rt] += (s0 + s1) + (s2 + s3);

            #pragma unroll
            for (int jt = 0; jt < 4; jt++) {
                ushort4 u;
                u.x = f2bf(p[jt][0]); u.y = f2bf(p[jt][1]);
                u.z = f2bf(p[jt][2]); u.w = f2bf(p[jt][3]);
                *(ushort4*)&Ps[w][lr][jt * 16 + lc * 4] = u;
            }
            short8 pb0 = *(const short8*)&Ps[w][lr][lc * 8];
            short8 pb1 = *(const short8*)&Ps[w][lr][32 + lc * 8];
            #pragma unroll
            for (int ct = 0; ct < 4; ct++) {
                o[rt][ct] = __builtin_amdgcn_mfma_f32_16x16x32_bf16(vf[ct][0], pb0, o[rt][ct], 0, 0, 0);
                o[rt][ct] = __builtin_amdgcn_mfma_f32_16x16x32_bf16(vf[ct][1], pb1, o[rt][ct], 0, 0, 0);
            }
        }

        if (more) {
            #pragma unroll
            for (int jt = 0; jt < 4; jt++) {
                kf[jt][0] = kn[jt][0];
                kf[jt][1] = kn[jt][1];
            }
        }
    }

    // reduce l across the 4 lc groups (once, not per tile)
    #pragma unroll
    for (int rt = 0; rt < 2; rt++) {
        l_[rt] += __shfl_xor(l_[rt], 16);
        l_[rt] += __shfl_xor(l_[rt], 32);
    }

    // ---- merge across 8 key-stripe waves: exact sums, 2 phases ----
    #pragma unroll
    for (int rt = 0; rt < 2; rt++) {
        #pragma unroll
        for (int ct = 0; ct < 4; ct++) Ol[w][ct][lane] = o[rt][ct];
        if (lc == 0) Ll[w][lr] = l_[rt];
        __syncthreads();

        // rt0 merged by waves 0..3 (ct=w), rt1 by waves 4..7 (ct=w-4)
        const bool mine = (rt == 0) ? (w < 4) : (w >= 4);
        if (mine) {
            const int ct = w & 3;
            float ltot = 0.f;
            #pragma unroll
            for (int ww = 0; ww < 8; ww++) ltot += Ll[ww][lr];
            float inv = 1.f / fmaxf(ltot, 1e-20f);
            float4v acc = Ol[0][ct][lane];
            #pragma unroll
            for (int ww = 1; ww < 8; ww++) {
                float4v a = Ol[ww][ct][lane];
                acc[0] += a[0]; acc[1] += a[1]; acc[2] += a[2]; acc[3] += a[3];
            }
            int qrow = q0 + rt * 16 + lr;
            ushort4 u;
            u.x = f2bf(acc[0] * inv);
            u.y = f2bf(acc[1] * inv);
            u.z = f2bf(acc[2] * inv);
            u.w = f2bf(acc[3] * inv);
            *(ushort4*)&Yb[((size_t)b * TT + qrow) * CC + h * 64 + ct * 16 + lc * 4] = u;
        }
        if (rt == 0) __syncthreads();   // protect Ol/Ll before phase-2 overwrite
    }
}

// ---------------------------------------------------------------------------
extern "C" void kernel_launch(void* const* d_in, const int* in_sizes, int n_in,
                              void* d_out, int out_size, void* d_ws, size_t ws_size,
                              hipStream_t stream) {
    (void)in_sizes; (void)n_in; (void)out_size; (void)ws_size;
    const float* x     = (const float*)d_in[0];
    const float* ve    = (const float*)d_in[1];
    const float* cosb  = (const float*)d_in[2];
    const float* sinb  = (const float*)d_in[3];
    const float* Wq    = (const float*)d_in[4];
    const float* Wk    = (const float*)d_in[5];
    const float* Wv    = (const float*)d_in[6];
    const float* Wproj = (const float*)d_in[7];
    const float* Wgate = (const float*)d_in[8];
    const int*   winp  = (const int*)d_in[9];
    float* out = (float*)d_out;

    char* ws = (char*)d_ws;
    float*  qkv   = (float*)ws;                      // 32 MiB (dead after qkv_post)
    ushort* Yb    = (ushort*)ws;                     // 8 MiB, overlays qkv
    ushort* xb    = (ushort*)(ws + 33554432);        // 8 MiB (dead after QKV GEMM)
    ushort* Vnb   = (ushort*)(ws + 33554432);        // 4 MiB natural V, overlays xb
    ushort* WqkvT = (ushort*)(ws + 41943040);        // 4 MiB: [2048][1024] = W^T
    ushort* WpT   = (ushort*)(ws + 46137344);        // 2 MiB: [1024][1024] = Wproj^T
    ushort* Qb    = (ushort*)(ws + 48234496);        // 8 MiB
    ushort* Kb    = (ushort*)(ws + 56623104);        // 4 MiB
    ushort* Vtb   = (ushort*)(ws + 60817408);        // 4 MiB (B,NKV,HD,T)

    dim3 blk(256);
    prep_kernel<<<dim3(4864), blk, 0, stream>>>(x, xb, Wq, Wk, Wv, Wproj, WqkvT, WpT);
    gemm_bt_kernel<128><<<dim3(32, 16), blk, 0, stream>>>(xb, WqkvT, qkv, 4096, 2048, 1024, 2048);
    qkv_post_kernel<<<dim3(BB * TT), blk, 0, stream>>>(qkv, x, ve, cosb, sinb, Wgate, Qb, Kb, Vnb);
    v_transpose_kernel<<<dim3(TT / 64, BB * NKV), blk, 0, stream>>>(Vnb, Vtb);
    // attention: 2048 blocks x 8 key-stripe waves, XCD-grouped, heavy-first
    attn_kernel<<<dim3(2048), dim3(512), 0, stream>>>(Qb, Kb, Vtb, Yb, winp);
    gemm_bt_kernel<64><<<dim3(64, 8), blk, 0, stream>>>(Yb, WpT, out, 4096, 1024, 1024, 1024);
}

// Round 10
// 222.075 us; speedup vs baseline: 1.1293x; 1.1293x over previous
//
#include <hip/hip_runtime.h>
#include <hip/hip_bf16.h>

// Problem constants (B=2, T=2048, C=1024, NH=16, NKV=8, HD=64, Q_PER_KV=2)
#define BB 2
#define TT 2048
#define CC 1024
#define NH 16
#define NKV 8
#define HD 64

typedef __attribute__((ext_vector_type(8))) short short8;   // 8 bf16 (MFMA A/B frag)
typedef __attribute__((ext_vector_type(4))) float float4v;  // MFMA C/D frag

__device__ __forceinline__ ushort f2bf(float f) {
    __hip_bfloat16 h = __float2bfloat16(f);
    union { __hip_bfloat16 h; ushort u; } v; v.h = h; return v.u;
}
__device__ __forceinline__ float bf2f(ushort u) {
    union { unsigned int i; float f; } v; v.i = ((unsigned int)u) << 16; return v.f;
}

// async global->LDS, 16B per lane; lptr must be wave-uniform, HW adds lane*16
__device__ __forceinline__ void gload16(const ushort* g, ushort* l) {
    __builtin_amdgcn_global_load_lds(
        (const __attribute__((address_space(1))) unsigned int*)g,
        (__attribute__((address_space(3))) unsigned int*)l, 16, 0, 0);
}

// ---------------------------------------------------------------------------
// Fused prep: x f32->bf16 conv (blocks 0..4095) + weight transposes
// (f32 [K][N] -> bf16 [N][K], 64x64 LDS tiles). One launch instead of 5.
// ---------------------------------------------------------------------------
__device__ __forceinline__ void transpose_tile(
    const float* __restrict__ src, ushort* __restrict__ dst,
    int Kd, int Nd, int kt, int nt, float* tile /*[64][65]*/)
{
    const int tid = threadIdx.x;
    {
        int r = tid >> 2, c = (tid & 3) * 16;
        #pragma unroll
        for (int i = 0; i < 4; i++) {
            float4 v = *(const float4*)&src[(size_t)(kt + r) * Nd + nt + c + i * 4];
            tile[r * 65 + c + i * 4 + 0] = v.x;
            tile[r * 65 + c + i * 4 + 1] = v.y;
            tile[r * 65 + c + i * 4 + 2] = v.z;
            tile[r * 65 + c + i * 4 + 3] = v.w;
        }
    }
    __syncthreads();
    {
        int n = tid >> 2, k = (tid & 3) * 16;
        #pragma unroll
        for (int i = 0; i < 2; i++) {
            ushort u[8];
            #pragma unroll
            for (int j = 0; j < 8; j++) u[j] = f2bf(tile[(k + i * 8 + j) * 65 + n]);
            *(uint4*)&dst[(size_t)(nt + n) * Kd + kt + k + i * 8] = *(uint4*)u;
        }
    }
}

__global__ __launch_bounds__(256) void prep_kernel(
    const float* __restrict__ x, ushort* __restrict__ xb,
    const float* __restrict__ Wq, const float* __restrict__ Wk,
    const float* __restrict__ Wv, const float* __restrict__ Wproj,
    ushort* __restrict__ WqkvT, ushort* __restrict__ WpT)
{
    __shared__ float tile[64 * 65];
    const int bid = blockIdx.x;
    if (bid < 4096) {
        int i = (bid * 256 + threadIdx.x) * 4;
        float4 v = *(const float4*)&x[i];
        xb[i + 0] = f2bf(v.x);
        xb[i + 1] = f2bf(v.y);
        xb[i + 2] = f2bf(v.z);
        xb[i + 3] = f2bf(v.w);
        return;
    }
    int t = bid - 4096;
    if (t < 256) {
        transpose_tile(Wq, WqkvT, 1024, 1024, (t >> 4) * 64, (t & 15) * 64, tile);
    } else if (t < 384) {
        t -= 256;
        transpose_tile(Wk, WqkvT + (size_t)1024 * 1024, 1024, 512, (t >> 3) * 64, (t & 7) * 64, tile);
    } else if (t < 512) {
        t -= 384;
        transpose_tile(Wv, WqkvT + (size_t)1536 * 1024, 1024, 512, (t >> 3) * 64, (t & 7) * 64, tile);
    } else {
        t -= 512;
        transpose_tile(Wproj, WpT, 1024, 1024, (t >> 4) * 64, (t & 15) * 64, tile);
    }
}

// ---------------------------------------------------------------------------
// bf16 GEMM (m97 structure): C = A @ Bt^T. A[M][K], Bt[N][K] row-major bf16.
// OBF16=1 -> C bf16, else C f32. Tile BMx128, BK=32, 4 waves;
// global_load_lds staging, no conflicts.
// ---------------------------------------------------------------------------
template<int BM, int OBF16>
__global__ __launch_bounds__(256) void gemm_bt_kernel(
    const ushort* __restrict__ A, const ushort* __restrict__ Bt,
    void* __restrict__ Cp, int M, int N, int K, int ldc)
{
    constexpr int RT = BM / 32;
    __shared__ ushort As[BM][32];
    __shared__ ushort Bs[128][32];

    const int m0 = blockIdx.x * BM;
    const int n0 = blockIdx.y * 128;
    const int tid = threadIdx.x;
    const int lane = tid & 63;
    const int w = tid >> 6;
    const int lr = lane & 15, lc = lane >> 4;
    const int wm = (w >> 1) * (BM / 2), wn = (w & 1) * 64;

    float4v acc[RT][4] = {};

    for (int k0 = 0; k0 < K; k0 += 32) {
        #pragma unroll
        for (int s = 0; s < BM / 64; s++) {
            int rb = w * (BM / 4) + s * 16;
            gload16(&A[(size_t)(m0 + rb + (lane >> 2)) * K + k0 + (lane & 3) * 8], &As[rb][0]);
        }
        #pragma unroll
        for (int s = 0; s < 2; s++) {
            int rb = w * 32 + s * 16;
            gload16(&Bt[(size_t)(n0 + rb + (lane >> 2)) * K + k0 + (lane & 3) * 8], &Bs[rb][0]);
        }
        __syncthreads();

        short8 af[RT], bf[4];
        #pragma unroll
        for (int t = 0; t < RT; t++)
            af[t] = *(const short8*)&As[wm + t * 16 + lr][lc * 8];
        #pragma unroll
        for (int t = 0; t < 4; t++)
            bf[t] = *(const short8*)&Bs[wn + t * 16 + lr][lc * 8];
        #pragma unroll
        for (int rt = 0; rt < RT; rt++)
            #pragma unroll
            for (int ct = 0; ct < 4; ct++)
                acc[rt][ct] = __builtin_amdgcn_mfma_f32_16x16x32_bf16(af[rt], bf[ct], acc[rt][ct], 0, 0, 0);
        __syncthreads();
    }

    #pragma unroll
    for (int rt = 0; rt < RT; rt++)
        #pragma unroll
        for (int ct = 0; ct < 4; ct++)
            #pragma unroll
            for (int r = 0; r < 4; r++) {
                int row = m0 + wm + rt * 16 + lc * 4 + r;
                int col = n0 + wn + ct * 16 + lr;
                if (OBF16) ((ushort*)Cp)[(size_t)row * ldc + col] = f2bf(acc[rt][ct][r]);
                else       ((float*)Cp)[(size_t)row * ldc + col] = acc[rt][ct][r];
            }
}

// ---------------------------------------------------------------------------
// Per-(b,t): gate + ve-add, RoPE + RMSNorm. qkv row = [q|k|v] BF16 (2048).
// Writes Q (B,NH,T,HD), K (B,NKV,T,HD), V natural (B,NKV,T,HD) — coalesced.
// ---------------------------------------------------------------------------
__global__ __launch_bounds__(256) void qkv_post_kernel(
    const ushort* __restrict__ qkv, const float* __restrict__ x,
    const float* __restrict__ ve, const float* __restrict__ cosb,
    const float* __restrict__ sinb, const float* __restrict__ wgate,
    ushort* __restrict__ Qb, ushort* __restrict__ Kb, ushort* __restrict__ Vn)
{
    const int bt = blockIdx.x;
    const int b = bt >> 11, t = bt & 2047;
    const int tid = threadIdx.x;
    const int lane = tid & 63;
    const int w = tid >> 6;
    __shared__ float gateS[8];

    {
        int g = tid >> 5, i = tid & 31;
        float p = x[(size_t)bt * CC + i] * wgate[i * 8 + g];
        #pragma unroll
        for (int off = 16; off; off >>= 1) p += __shfl_down(p, off, 32);
        if (i == 0) gateS[g] = 2.f / (1.f + __expf(-p));
    }
    __syncthreads();

    const float c = cosb[t * 32 + (lane & 31)];
    const float s = sinb[t * 32 + (lane & 31)];
    for (int hh = w; hh < 24; hh += 4) {
        const ushort* z = &qkv[(size_t)bt * 2048 + hh * 64];
        float v = bf2f(z[lane]);
        float other = __shfl_xor(v, 32);
        float x1 = (lane < 32) ? v : other;
        float x2 = (lane < 32) ? other : v;
        float val = (lane < 32) ? (x1 * c + x2 * s) : (-x1 * s + x2 * c);
        float ss = val * val;
        #pragma unroll
        for (int off = 32; off; off >>= 1) ss += __shfl_xor(ss, off);
        float scale = rsqrtf(ss * (1.f / 64.f) + 1.1920929e-07f);
        ushort ob = f2bf(val * scale);
        if (hh < 16) Qb[(((size_t)b * NH + hh) * TT + t) * HD + lane] = ob;
        else         Kb[(((size_t)b * NKV + (hh - 16)) * TT + t) * HD + lane] = ob;
    }

    for (int e = tid; e < NKV * HD; e += 256) {
        int kh = e >> 6, d = e & 63;
        float v = bf2f(qkv[(size_t)bt * 2048 + 1536 + e]) + gateS[kh] * ve[(size_t)bt * 512 + e];
        Vn[(((size_t)b * NKV + kh) * TT + t) * HD + d] = f2bf(v);
    }
}

// ---------------------------------------------------------------------------
// V natural (B,NKV,T,HD) -> V^T (B,NKV,HD,T): LDS-tiled, coalesced both ways.
// ---------------------------------------------------------------------------
__global__ __launch_bounds__(256) void v_transpose_kernel(
    const ushort* __restrict__ Vn, ushort* __restrict__ Vt)
{
    __shared__ ushort tile[64][72];
    const int t0 = blockIdx.x * 64;
    const int bh = blockIdx.y;
    const ushort* src = &Vn[(size_t)bh * TT * HD + (size_t)t0 * HD];
    ushort* dst = &Vt[(size_t)bh * HD * TT + t0];
    const int tid = threadIdx.x;
    {
        int r = tid >> 2, c = (tid & 3) * 16;
        #pragma unroll
        for (int i = 0; i < 2; i++)
            *(uint4*)&tile[r][c + i * 8] = *(const uint4*)&src[(size_t)r * HD + c + i * 8];
    }
    __syncthreads();
    {
        int d = tid >> 2, c = (tid & 3) * 16;
        #pragma unroll
        for (int i = 0; i < 2; i++) {
            ushort u[8];
            #pragma unroll
            for (int j = 0; j < 8; j++) u[j] = tile[c + i * 8 + j][d];
            *(uint4*)&dst[(size_t)d * TT + c + i * 8] = *(uint4*)u;
        }
    }
}

// ---------------------------------------------------------------------------
// Split-KV flash attention (round-8 config, empirically best): 4 waves/block
// striping key tiles stride-4; unnormalized exp (q,k RMS-normed -> f32-safe);
// exact-sum merge over 4 partials; heavy-first mapping.
// ---------------------------------------------------------------------------
__global__ __launch_bounds__(256) void attn_kernel(
    const ushort* __restrict__ Qb, const ushort* __restrict__ Kb,
    const ushort* __restrict__ Vt, ushort* __restrict__ Yb,
    const int* __restrict__ winp)
{
    const int gid = blockIdx.x;
    int b, h, qw;
    if (gid < 1024) { qw = 63 - (gid >> 4); h = (gid >> 1) & 7; b = gid & 1; }
    else { int j = gid - 1024; qw = 63 - (j >> 4); h = 8 + ((j >> 1) & 7); b = j & 1; }

    const int q0 = qw * 32;
    const int kvh = h >> 1;
    const bool local = (h >= 8);
    int window = *winp;
    if (window < 0 || window > TT) window = TT;
    const int tid = threadIdx.x;
    const int w = tid >> 6;
    const int lane = tid & 63;
    const int lr = lane & 15, lc = lane >> 4;

    __shared__ ushort Ps[4][16][72];
    __shared__ float4v Ol[4][4][64];
    __shared__ float Ll[4][16];

    const ushort* qbase = &Qb[(((size_t)b * NH + h) * TT + q0) * HD];
    short8 qf[2][2];
    #pragma unroll
    for (int rt = 0; rt < 2; rt++)
        #pragma unroll
        for (int xh = 0; xh < 2; xh++)
            qf[rt][xh] = *(const short8*)&qbase[(size_t)(rt * 16 + lr) * HD + xh * 32 + lc * 8];

    float4v o[2][4] = {};
    float l_[2] = {0.f, 0.f};

    const ushort* Kbase = &Kb[((size_t)b * NKV + kvh) * TT * HD];
    const ushort* Vbase = &Vt[((size_t)b * NKV + kvh) * HD * TT];

    const int qlast = q0 + 31;
    int jstart = 0;
    if (local) { int js = q0 - window; if (js > 0) jstart = js & ~63; }
    const int j0first = jstart + w * 64;

    short8 kf[4][2];
    if (j0first <= qlast) {
        #pragma unroll
        for (int jt = 0; jt < 4; jt++) {
            const ushort* kp = &Kbase[(size_t)(j0first + jt * 16 + lr) * HD + lc * 8];
            kf[jt][0] = *(const short8*)kp;
            kf[jt][1] = *(const short8*)(kp + 32);
        }
    }

    for (int j0 = j0first; j0 <= qlast; j0 += 256) {
        short8 vf[4][2];
        #pragma unroll
        for (int ct = 0; ct < 4; ct++) {
            const ushort* vp = &Vbase[(size_t)(ct * 16 + lr) * TT + j0 + lc * 8];
            vf[ct][0] = *(const short8*)vp;
            vf[ct][1] = *(const short8*)(vp + 32);
        }
        short8 kn[4][2];
        const bool more = (j0 + 256 <= qlast);
        if (more) {
            #pragma unroll
            for (int jt = 0; jt < 4; jt++) {
                const ushort* kp = &Kbase[(size_t)(j0 + 256 + jt * 16 + lr) * HD + lc * 8];
                kn[jt][0] = *(const short8*)kp;
                kn[jt][1] = *(const short8*)(kp + 32);
            }
        }

        float4v st[2][4];
        #pragma unroll
        for (int jt = 0; jt < 4; jt++)
            #pragma unroll
            for (int rt = 0; rt < 2; rt++) {
                float4v z = {};
                z = __builtin_amdgcn_mfma_f32_16x16x32_bf16(kf[jt][0], qf[rt][0], z, 0, 0, 0);
                z = __builtin_amdgcn_mfma_f32_16x16x32_bf16(kf[jt][1], qf[rt][1], z, 0, 0, 0);
                st[rt][jt] = z;
            }

        const bool need_c = (j0 + 63 > q0);
        const bool need_w = local && (j0 < qlast - window);

        #pragma unroll
        for (int rt = 0; rt < 2; rt++) {
            const int qrow = q0 + rt * 16 + lr;
            float p[4][4];
            if (need_c || need_w) {
                #pragma unroll
                for (int jt = 0; jt < 4; jt++)
                    #pragma unroll
                    for (int r = 0; r < 4; r++) {
                        int key = j0 + jt * 16 + lc * 4 + r;
                        bool ok = (key <= qrow) && (!local || key >= qrow - window);
                        p[jt][r] = ok ? __expf(st[rt][jt][r] * 0.125f) : 0.f;
                    }
            } else {
                #pragma unroll
                for (int jt = 0; jt < 4; jt++)
                    #pragma unroll
                    for (int r = 0; r < 4; r++)
                        p[jt][r] = __expf(st[rt][jt][r] * 0.125f);
            }
            float s0 = (p[0][0] + p[0][1]) + (p[0][2] + p[0][3]);
            float s1 = (p[1][0] + p[1][1]) + (p[1][2] + p[1][3]);
            float s2 = (p[2][0] + p[2][1]) + (p[2][2] + p[2][3]);
            float s3 = (p[3][0] + p[3][1]) + (p[3][2] + p[3][3]);
            l_[rt] += (s0 + s1) + (s2 + s3);

            #pragma unroll
            for (int jt = 0; jt < 4; jt++) {
                ushort4 u;
                u.x = f2bf(p[jt][0]); u.y = f2bf(p[jt][1]);
                u.z = f2bf(p[jt][2]); u.w = f2bf(p[jt][3]);
                *(ushort4*)&Ps[w][lr][jt * 16 + lc * 4] = u;
            }
            short8 pb0 = *(const short8*)&Ps[w][lr][lc * 8];
            short8 pb1 = *(const short8*)&Ps[w][lr][32 + lc * 8];
            #pragma unroll
            for (int ct = 0; ct < 4; ct++) {
                o[rt][ct] = __builtin_amdgcn_mfma_f32_16x16x32_bf16(vf[ct][0], pb0, o[rt][ct], 0, 0, 0);
                o[rt][ct] = __builtin_amdgcn_mfma_f32_16x16x32_bf16(vf[ct][1], pb1, o[rt][ct], 0, 0, 0);
            }
        }

        if (more) {
            #pragma unroll
            for (int jt = 0; jt < 4; jt++) {
                kf[jt][0] = kn[jt][0];
                kf[jt][1] = kn[jt][1];
            }
        }
    }

    #pragma unroll
    for (int rt = 0; rt < 2; rt++) {
        l_[rt] += __shfl_xor(l_[rt], 16);
        l_[rt] += __shfl_xor(l_[rt], 32);
    }

    #pragma unroll
    for (int rt = 0; rt < 2; rt++) {
        #pragma unroll
        for (int ct = 0; ct < 4; ct++) Ol[w][ct][lane] = o[rt][ct];
        if (lc == 0) Ll[w][lr] = l_[rt];
        __syncthreads();

        {
            const int ct = w;
            float ltot = (Ll[0][lr] + Ll[1][lr]) + (Ll[2][lr] + Ll[3][lr]);
            float inv = 1.f / fmaxf(ltot, 1e-20f);
            float4v a0 = Ol[0][ct][lane], a1 = Ol[1][ct][lane];
            float4v a2 = Ol[2][ct][lane], a3 = Ol[3][ct][lane];
            int qrow = q0 + rt * 16 + lr;
            ushort4 u;
            u.x = f2bf(((a0[0] + a1[0]) + (a2[0] + a3[0])) * inv);
            u.y = f2bf(((a0[1] + a1[1]) + (a2[1] + a3[1])) * inv);
            u.z = f2bf(((a0[2] + a1[2]) + (a2[2] + a3[2])) * inv);
            u.w = f2bf(((a0[3] + a1[3]) + (a2[3] + a3[3])) * inv);
            *(ushort4*)&Yb[((size_t)b * TT + qrow) * CC + h * 64 + ct * 16 + lc * 4] = u;
        }
        if (rt == 0) __syncthreads();
    }
}

// ---------------------------------------------------------------------------
extern "C" void kernel_launch(void* const* d_in, const int* in_sizes, int n_in,
                              void* d_out, int out_size, void* d_ws, size_t ws_size,
                              hipStream_t stream) {
    (void)in_sizes; (void)n_in; (void)out_size; (void)ws_size;
    const float* x     = (const float*)d_in[0];
    const float* ve    = (const float*)d_in[1];
    const float* cosb  = (const float*)d_in[2];
    const float* sinb  = (const float*)d_in[3];
    const float* Wq    = (const float*)d_in[4];
    const float* Wk    = (const float*)d_in[5];
    const float* Wv    = (const float*)d_in[6];
    const float* Wproj = (const float*)d_in[7];
    const float* Wgate = (const float*)d_in[8];
    const int*   winp  = (const int*)d_in[9];
    float* out = (float*)d_out;

    char* ws = (char*)d_ws;
    ushort* qkvb  = (ushort*)ws;                     // 16 MiB bf16 (dead after qkv_post)
    ushort* Yb    = (ushort*)ws;                     // 8 MiB, overlays qkvb
    ushort* xb    = (ushort*)(ws + 33554432);        // 8 MiB (dead after QKV GEMM)
    ushort* Vnb   = (ushort*)(ws + 33554432);        // 4 MiB natural V, overlays xb
    ushort* WqkvT = (ushort*)(ws + 41943040);        // 4 MiB: [2048][1024] = W^T
    ushort* WpT   = (ushort*)(ws + 46137344);        // 2 MiB: [1024][1024] = Wproj^T
    ushort* Qb    = (ushort*)(ws + 48234496);        // 8 MiB
    ushort* Kb    = (ushort*)(ws + 56623104);        // 4 MiB
    ushort* Vtb   = (ushort*)(ws + 60817408);        // 4 MiB (B,NKV,HD,T)

    dim3 blk(256);
    prep_kernel<<<dim3(4864), blk, 0, stream>>>(x, xb, Wq, Wk, Wv, Wproj, WqkvT, WpT);
    // fused QKV projection -> bf16 qkv intermediate (halves write+read traffic)
    gemm_bt_kernel<128, 1><<<dim3(32, 16), blk, 0, stream>>>(xb, WqkvT, qkvb, 4096, 2048, 1024, 2048);
    qkv_post_kernel<<<dim3(BB * TT), blk, 0, stream>>>(qkvb, x, ve, cosb, sinb, Wgate, Qb, Kb, Vnb);
    v_transpose_kernel<<<dim3(TT / 64, BB * NKV), blk, 0, stream>>>(Vnb, Vtb);
    // attention: round-8 config (4 waves, stride-4 striping, heavy-first)
    attn_kernel<<<dim3(2048), blk, 0, stream>>>(Qb, Kb, Vtb, Yb, winp);
    // output projection -> f32 d_out (BM=64: 512 blocks, 2/CU)
    gemm_bt_kernel<64, 0><<<dim3(64, 8), blk, 0, stream>>>(Yb, WpT, out, 4096, 1024, 1024, 1024);
}

// Round 11
// 222.044 us; speedup vs baseline: 1.1294x; 1.0001x over previous
//
#include <hip/hip_runtime.h>
#include <hip/hip_bf16.h>

// Problem constants (B=2, T=2048, C=1024, NH=16, NKV=8, HD=64, Q_PER_KV=2)
#define BB 2
#define TT 2048
#define CC 1024
#define NH 16
#define NKV 8
#define HD 64

typedef __attribute__((ext_vector_type(8))) short short8;   // 8 bf16 (MFMA A/B frag)
typedef __attribute__((ext_vector_type(4))) float float4v;  // MFMA C/D frag

__device__ __forceinline__ ushort f2bf(float f) {
    __hip_bfloat16 h = __float2bfloat16(f);
    union { __hip_bfloat16 h; ushort u; } v; v.h = h; return v.u;
}
__device__ __forceinline__ float bf2f(ushort u) {
    union { unsigned int i; float f; } v; v.i = ((unsigned int)u) << 16; return v.f;
}

// async global->LDS, 16B per lane; lptr must be wave-uniform, HW adds lane*16
__device__ __forceinline__ void gload16(const ushort* g, ushort* l) {
    __builtin_amdgcn_global_load_lds(
        (const __attribute__((address_space(1))) unsigned int*)g,
        (__attribute__((address_space(3))) unsigned int*)l, 16, 0, 0);
}

// ---------------------------------------------------------------------------
// Fused prep: x f32->bf16 conv (blocks 0..4095) + weight transposes
// (f32 [K][N] -> bf16 [N][K], 64x64 LDS tiles). One launch instead of 5.
// ---------------------------------------------------------------------------
__device__ __forceinline__ void transpose_tile(
    const float* __restrict__ src, ushort* __restrict__ dst,
    int Kd, int Nd, int kt, int nt, float* tile /*[64][65]*/)
{
    const int tid = threadIdx.x;
    {
        int r = tid >> 2, c = (tid & 3) * 16;
        #pragma unroll
        for (int i = 0; i < 4; i++) {
            float4 v = *(const float4*)&src[(size_t)(kt + r) * Nd + nt + c + i * 4];
            tile[r * 65 + c + i * 4 + 0] = v.x;
            tile[r * 65 + c + i * 4 + 1] = v.y;
            tile[r * 65 + c + i * 4 + 2] = v.z;
            tile[r * 65 + c + i * 4 + 3] = v.w;
        }
    }
    __syncthreads();
    {
        int n = tid >> 2, k = (tid & 3) * 16;
        #pragma unroll
        for (int i = 0; i < 2; i++) {
            ushort u[8];
            #pragma unroll
            for (int j = 0; j < 8; j++) u[j] = f2bf(tile[(k + i * 8 + j) * 65 + n]);
            *(uint4*)&dst[(size_t)(nt + n) * Kd + kt + k + i * 8] = *(uint4*)u;
        }
    }
}

__global__ __launch_bounds__(256) void prep_kernel(
    const float* __restrict__ x, ushort* __restrict__ xb,
    const float* __restrict__ Wq, const float* __restrict__ Wk,
    const float* __restrict__ Wv, const float* __restrict__ Wproj,
    ushort* __restrict__ WqkvT, ushort* __restrict__ WpT)
{
    __shared__ float tile[64 * 65];
    const int bid = blockIdx.x;
    if (bid < 4096) {
        int i = (bid * 256 + threadIdx.x) * 4;
        float4 v = *(const float4*)&x[i];
        xb[i + 0] = f2bf(v.x);
        xb[i + 1] = f2bf(v.y);
        xb[i + 2] = f2bf(v.z);
        xb[i + 3] = f2bf(v.w);
        return;
    }
    int t = bid - 4096;
    if (t < 256) {
        transpose_tile(Wq, WqkvT, 1024, 1024, (t >> 4) * 64, (t & 15) * 64, tile);
    } else if (t < 384) {
        t -= 256;
        transpose_tile(Wk, WqkvT + (size_t)1024 * 1024, 1024, 512, (t >> 3) * 64, (t & 7) * 64, tile);
    } else if (t < 512) {
        t -= 384;
        transpose_tile(Wv, WqkvT + (size_t)1536 * 1024, 1024, 512, (t >> 3) * 64, (t & 7) * 64, tile);
    } else {
        t -= 512;
        transpose_tile(Wproj, WpT, 1024, 1024, (t >> 4) * 64, (t & 15) * 64, tile);
    }
}

// ---------------------------------------------------------------------------
// bf16 GEMM (m97 structure): C = A @ Bt^T. A[M][K], Bt[N][K] row-major bf16.
// OBF16=1 -> C bf16, else C f32. Tile BMx128, BK=32, 4 waves.
// BM=64 -> RT=2, 12 KB LDS, ~2x the blocks (occupancy: hide the vmcnt drain).
// ---------------------------------------------------------------------------
template<int BM, int OBF16>
__global__ __launch_bounds__(256) void gemm_bt_kernel(
    const ushort* __restrict__ A, const ushort* __restrict__ Bt,
    void* __restrict__ Cp, int M, int N, int K, int ldc)
{
    constexpr int RT = BM / 32;
    __shared__ ushort As[BM][32];
    __shared__ ushort Bs[128][32];

    const int m0 = blockIdx.x * BM;
    const int n0 = blockIdx.y * 128;
    const int tid = threadIdx.x;
    const int lane = tid & 63;
    const int w = tid >> 6;
    const int lr = lane & 15, lc = lane >> 4;
    const int wm = (w >> 1) * (BM / 2), wn = (w & 1) * 64;

    float4v acc[RT][4] = {};

    for (int k0 = 0; k0 < K; k0 += 32) {
        #pragma unroll
        for (int s = 0; s < BM / 64; s++) {          // BM=64: 1 instr/wave
            int rb = w * (BM / 4) + s * 16;
            gload16(&A[(size_t)(m0 + rb + (lane >> 2)) * K + k0 + (lane & 3) * 8], &As[rb][0]);
        }
        #pragma unroll
        for (int s = 0; s < 2; s++) {
            int rb = w * 32 + s * 16;
            gload16(&Bt[(size_t)(n0 + rb + (lane >> 2)) * K + k0 + (lane & 3) * 8], &Bs[rb][0]);
        }
        __syncthreads();

        short8 af[RT], bf[4];
        #pragma unroll
        for (int t = 0; t < RT; t++)
            af[t] = *(const short8*)&As[wm + t * 16 + lr][lc * 8];
        #pragma unroll
        for (int t = 0; t < 4; t++)
            bf[t] = *(const short8*)&Bs[wn + t * 16 + lr][lc * 8];
        #pragma unroll
        for (int rt = 0; rt < RT; rt++)
            #pragma unroll
            for (int ct = 0; ct < 4; ct++)
                acc[rt][ct] = __builtin_amdgcn_mfma_f32_16x16x32_bf16(af[rt], bf[ct], acc[rt][ct], 0, 0, 0);
        __syncthreads();
    }

    #pragma unroll
    for (int rt = 0; rt < RT; rt++)
        #pragma unroll
        for (int ct = 0; ct < 4; ct++)
            #pragma unroll
            for (int r = 0; r < 4; r++) {
                int row = m0 + wm + rt * 16 + lc * 4 + r;
                int col = n0 + wn + ct * 16 + lr;
                if (OBF16) ((ushort*)Cp)[(size_t)row * ldc + col] = f2bf(acc[rt][ct][r]);
                else       ((float*)Cp)[(size_t)row * ldc + col] = acc[rt][ct][r];
            }
}

// ---------------------------------------------------------------------------
// Per-(b,t): gate + ve-add, RoPE + RMSNorm. qkv row = [q|k|v] BF16 (2048).
// Writes Q (B,NH,T,HD), K (B,NKV,T,HD), V natural (B,NKV,T,HD) — coalesced.
// ---------------------------------------------------------------------------
__global__ __launch_bounds__(256) void qkv_post_kernel(
    const ushort* __restrict__ qkv, const float* __restrict__ x,
    const float* __restrict__ ve, const float* __restrict__ cosb,
    const float* __restrict__ sinb, const float* __restrict__ wgate,
    ushort* __restrict__ Qb, ushort* __restrict__ Kb, ushort* __restrict__ Vn)
{
    const int bt = blockIdx.x;
    const int b = bt >> 11, t = bt & 2047;
    const int tid = threadIdx.x;
    const int lane = tid & 63;
    const int w = tid >> 6;
    __shared__ float gateS[8];

    {
        int g = tid >> 5, i = tid & 31;
        float p = x[(size_t)bt * CC + i] * wgate[i * 8 + g];
        #pragma unroll
        for (int off = 16; off; off >>= 1) p += __shfl_down(p, off, 32);
        if (i == 0) gateS[g] = 2.f / (1.f + __expf(-p));
    }
    __syncthreads();

    const float c = cosb[t * 32 + (lane & 31)];
    const float s = sinb[t * 32 + (lane & 31)];
    for (int hh = w; hh < 24; hh += 4) {
        const ushort* z = &qkv[(size_t)bt * 2048 + hh * 64];
        float v = bf2f(z[lane]);
        float other = __shfl_xor(v, 32);
        float x1 = (lane < 32) ? v : other;
        float x2 = (lane < 32) ? other : v;
        float val = (lane < 32) ? (x1 * c + x2 * s) : (-x1 * s + x2 * c);
        float ss = val * val;
        #pragma unroll
        for (int off = 32; off; off >>= 1) ss += __shfl_xor(ss, off);
        float scale = rsqrtf(ss * (1.f / 64.f) + 1.1920929e-07f);
        ushort ob = f2bf(val * scale);
        if (hh < 16) Qb[(((size_t)b * NH + hh) * TT + t) * HD + lane] = ob;
        else         Kb[(((size_t)b * NKV + (hh - 16)) * TT + t) * HD + lane] = ob;
    }

    for (int e = tid; e < NKV * HD; e += 256) {
        int kh = e >> 6, d = e & 63;
        float v = bf2f(qkv[(size_t)bt * 2048 + 1536 + e]) + gateS[kh] * ve[(size_t)bt * 512 + e];
        Vn[(((size_t)b * NKV + kh) * TT + t) * HD + d] = f2bf(v);
    }
}

// ---------------------------------------------------------------------------
// V natural (B,NKV,T,HD) -> V^T (B,NKV,HD,T): LDS-tiled, coalesced both ways.
// ---------------------------------------------------------------------------
__global__ __launch_bounds__(256) void v_transpose_kernel(
    const ushort* __restrict__ Vn, ushort* __restrict__ Vt)
{
    __shared__ ushort tile[64][72];
    const int t0 = blockIdx.x * 64;
    const int bh = blockIdx.y;
    const ushort* src = &Vn[(size_t)bh * TT * HD + (size_t)t0 * HD];
    ushort* dst = &Vt[(size_t)bh * HD * TT + t0];
    const int tid = threadIdx.x;
    {
        int r = tid >> 2, c = (tid & 3) * 16;
        #pragma unroll
        for (int i = 0; i < 2; i++)
            *(uint4*)&tile[r][c + i * 8] = *(const uint4*)&src[(size_t)r * HD + c + i * 8];
    }
    __syncthreads();
    {
        int d = tid >> 2, c = (tid & 3) * 16;
        #pragma unroll
        for (int i = 0; i < 2; i++) {
            ushort u[8];
            #pragma unroll
            for (int j = 0; j < 8; j++) u[j] = tile[c + i * 8 + j][d];
            *(uint4*)&dst[(size_t)d * TT + c + i * 8] = *(uint4*)u;
        }
    }
}

// ---------------------------------------------------------------------------
// Split-KV flash attention (round-8 config, empirically best): 4 waves/block
// striping key tiles stride-4; unnormalized exp (q,k RMS-normed -> f32-safe);
// exact-sum merge over 4 partials; heavy-first mapping. FROZEN.
// ---------------------------------------------------------------------------
__global__ __launch_bounds__(256) void attn_kernel(
    const ushort* __restrict__ Qb, const ushort* __restrict__ Kb,
    const ushort* __restrict__ Vt, ushort* __restrict__ Yb,
    const int* __restrict__ winp)
{
    const int gid = blockIdx.x;
    int b, h, qw;
    if (gid < 1024) { qw = 63 - (gid >> 4); h = (gid >> 1) & 7; b = gid & 1; }
    else { int j = gid - 1024; qw = 63 - (j >> 4); h = 8 + ((j >> 1) & 7); b = j & 1; }

    const int q0 = qw * 32;
    const int kvh = h >> 1;
    const bool local = (h >= 8);
    int window = *winp;
    if (window < 0 || window > TT) window = TT;
    const int tid = threadIdx.x;
    const int w = tid >> 6;
    const int lane = tid & 63;
    const int lr = lane & 15, lc = lane >> 4;

    __shared__ ushort Ps[4][16][72];
    __shared__ float4v Ol[4][4][64];
    __shared__ float Ll[4][16];

    const ushort* qbase = &Qb[(((size_t)b * NH + h) * TT + q0) * HD];
    short8 qf[2][2];
    #pragma unroll
    for (int rt = 0; rt < 2; rt++)
        #pragma unroll
        for (int xh = 0; xh < 2; xh++)
            qf[rt][xh] = *(const short8*)&qbase[(size_t)(rt * 16 + lr) * HD + xh * 32 + lc * 8];

    float4v o[2][4] = {};
    float l_[2] = {0.f, 0.f};

    const ushort* Kbase = &Kb[((size_t)b * NKV + kvh) * TT * HD];
    const ushort* Vbase = &Vt[((size_t)b * NKV + kvh) * HD * TT];

    const int qlast = q0 + 31;
    int jstart = 0;
    if (local) { int js = q0 - window; if (js > 0) jstart = js & ~63; }
    const int j0first = jstart + w * 64;

    short8 kf[4][2];
    if (j0first <= qlast) {
        #pragma unroll
        for (int jt = 0; jt < 4; jt++) {
            const ushort* kp = &Kbase[(size_t)(j0first + jt * 16 + lr) * HD + lc * 8];
            kf[jt][0] = *(const short8*)kp;
            kf[jt][1] = *(const short8*)(kp + 32);
        }
    }

    for (int j0 = j0first; j0 <= qlast; j0 += 256) {
        short8 vf[4][2];
        #pragma unroll
        for (int ct = 0; ct < 4; ct++) {
            const ushort* vp = &Vbase[(size_t)(ct * 16 + lr) * TT + j0 + lc * 8];
            vf[ct][0] = *(const short8*)vp;
            vf[ct][1] = *(const short8*)(vp + 32);
        }
        short8 kn[4][2];
        const bool more = (j0 + 256 <= qlast);
        if (more) {
            #pragma unroll
            for (int jt = 0; jt < 4; jt++) {
                const ushort* kp = &Kbase[(size_t)(j0 + 256 + jt * 16 + lr) * HD + lc * 8];
                kn[jt][0] = *(const short8*)kp;
                kn[jt][1] = *(const short8*)(kp + 32);
            }
        }

        float4v st[2][4];
        #pragma unroll
        for (int jt = 0; jt < 4; jt++)
            #pragma unroll
            for (int rt = 0; rt < 2; rt++) {
                float4v z = {};
                z = __builtin_amdgcn_mfma_f32_16x16x32_bf16(kf[jt][0], qf[rt][0], z, 0, 0, 0);
                z = __builtin_amdgcn_mfma_f32_16x16x32_bf16(kf[jt][1], qf[rt][1], z, 0, 0, 0);
                st[rt][jt] = z;
            }

        const bool need_c = (j0 + 63 > q0);
        const bool need_w = local && (j0 < qlast - window);

        #pragma unroll
        for (int rt = 0; rt < 2; rt++) {
            const int qrow = q0 + rt * 16 + lr;
            float p[4][4];
            if (need_c || need_w) {
                #pragma unroll
                for (int jt = 0; jt < 4; jt++)
                    #pragma unroll
                    for (int r = 0; r < 4; r++) {
                        int key = j0 + jt * 16 + lc * 4 + r;
                        bool ok = (key <= qrow) && (!local || key >= qrow - window);
                        p[jt][r] = ok ? __expf(st[rt][jt][r] * 0.125f) : 0.f;
                    }
            } else {
                #pragma unroll
                for (int jt = 0; jt < 4; jt++)
                    #pragma unroll
                    for (int r = 0; r < 4; r++)
                        p[jt][r] = __expf(st[rt][jt][r] * 0.125f);
            }
            float s0 = (p[0][0] + p[0][1]) + (p[0][2] + p[0][3]);
            float s1 = (p[1][0] + p[1][1]) + (p[1][2] + p[1][3]);
            float s2 = (p[2][0] + p[2][1]) + (p[2][2] + p[2][3]);
            float s3 = (p[3][0] + p[3][1]) + (p[3][2] + p[3][3]);
            l_[rt] += (s0 + s1) + (s2 + s3);

            #pragma unroll
            for (int jt = 0; jt < 4; jt++) {
                ushort4 u;
                u.x = f2bf(p[jt][0]); u.y = f2bf(p[jt][1]);
                u.z = f2bf(p[jt][2]); u.w = f2bf(p[jt][3]);
                *(ushort4*)&Ps[w][lr][jt * 16 + lc * 4] = u;
            }
            short8 pb0 = *(const short8*)&Ps[w][lr][lc * 8];
            short8 pb1 = *(const short8*)&Ps[w][lr][32 + lc * 8];
            #pragma unroll
            for (int ct = 0; ct < 4; ct++) {
                o[rt][ct] = __builtin_amdgcn_mfma_f32_16x16x32_bf16(vf[ct][0], pb0, o[rt][ct], 0, 0, 0);
                o[rt][ct] = __builtin_amdgcn_mfma_f32_16x16x32_bf16(vf[ct][1], pb1, o[rt][ct], 0, 0, 0);
            }
        }

        if (more) {
            #pragma unroll
            for (int jt = 0; jt < 4; jt++) {
                kf[jt][0] = kn[jt][0];
                kf[jt][1] = kn[jt][1];
            }
        }
    }

    #pragma unroll
    for (int rt = 0; rt < 2; rt++) {
        l_[rt] += __shfl_xor(l_[rt], 16);
        l_[rt] += __shfl_xor(l_[rt], 32);
    }

    #pragma unroll
    for (int rt = 0; rt < 2; rt++) {
        #pragma unroll
        for (int ct = 0; ct < 4; ct++) Ol[w][ct][lane] = o[rt][ct];
        if (lc == 0) Ll[w][lr] = l_[rt];
        __syncthreads();

        {
            const int ct = w;
            float ltot = (Ll[0][lr] + Ll[1][lr]) + (Ll[2][lr] + Ll[3][lr]);
            float inv = 1.f / fmaxf(ltot, 1e-20f);
            float4v a0 = Ol[0][ct][lane], a1 = Ol[1][ct][lane];
            float4v a2 = Ol[2][ct][lane], a3 = Ol[3][ct][lane];
            int qrow = q0 + rt * 16 + lr;
            ushort4 u;
            u.x = f2bf(((a0[0] + a1[0]) + (a2[0] + a3[0])) * inv);
            u.y = f2bf(((a0[1] + a1[1]) + (a2[1] + a3[1])) * inv);
            u.z = f2bf(((a0[2] + a1[2]) + (a2[2] + a3[2])) * inv);
            u.w = f2bf(((a0[3] + a1[3]) + (a2[3] + a3[3])) * inv);
            *(ushort4*)&Yb[((size_t)b * TT + qrow) * CC + h * 64 + ct * 16 + lc * 4] = u;
        }
        if (rt == 0) __syncthreads();
    }
}

// ---------------------------------------------------------------------------
extern "C" void kernel_launch(void* const* d_in, const int* in_sizes, int n_in,
                              void* d_out, int out_size, void* d_ws, size_t ws_size,
                              hipStream_t stream) {
    (void)in_sizes; (void)n_in; (void)out_size; (void)ws_size;
    const float* x     = (const float*)d_in[0];
    const float* ve    = (const float*)d_in[1];
    const float* cosb  = (const float*)d_in[2];
    const float* sinb  = (const float*)d_in[3];
    const float* Wq    = (const float*)d_in[4];
    const float* Wk    = (const float*)d_in[5];
    const float* Wv    = (const float*)d_in[6];
    const float* Wproj = (const float*)d_in[7];
    const float* Wgate = (const float*)d_in[8];
    const int*   winp  = (const int*)d_in[9];
    float* out = (float*)d_out;

    char* ws = (char*)d_ws;
    ushort* qkvb  = (ushort*)ws;                     // 16 MiB bf16 (dead after qkv_post)
    ushort* Yb    = (ushort*)ws;                     // 8 MiB, overlays qkvb
    ushort* xb    = (ushort*)(ws + 33554432);        // 8 MiB (dead after QKV GEMM)
    ushort* Vnb   = (ushort*)(ws + 33554432);        // 4 MiB natural V, overlays xb
    ushort* WqkvT = (ushort*)(ws + 41943040);        // 4 MiB: [2048][1024] = W^T
    ushort* WpT   = (ushort*)(ws + 46137344);        // 2 MiB: [1024][1024] = Wproj^T
    ushort* Qb    = (ushort*)(ws + 48234496);        // 8 MiB
    ushort* Kb    = (ushort*)(ws + 56623104);        // 4 MiB
    ushort* Vtb   = (ushort*)(ws + 60817408);        // 4 MiB (B,NKV,HD,T)

    dim3 blk(256);
    prep_kernel<<<dim3(4864), blk, 0, stream>>>(x, xb, Wq, Wk, Wv, Wproj, WqkvT, WpT);
    // fused QKV projection -> bf16; BM=64: 1024 blocks = 4/CU (hide vmcnt drain)
    gemm_bt_kernel<64, 1><<<dim3(64, 16), blk, 0, stream>>>(xb, WqkvT, qkvb, 4096, 2048, 1024, 2048);
    qkv_post_kernel<<<dim3(BB * TT), blk, 0, stream>>>(qkvb, x, ve, cosb, sinb, Wgate, Qb, Kb, Vnb);
    v_transpose_kernel<<<dim3(TT / 64, BB * NKV), blk, 0, stream>>>(Vnb, Vtb);
    // attention: round-8 config, frozen
    attn_kernel<<<dim3(2048), blk, 0, stream>>>(Qb, Kb, Vtb, Yb, winp);
    // output projection -> f32 d_out; BM=64: 512 light blocks
    gemm_bt_kernel<64, 0><<<dim3(64, 8), blk, 0, stream>>>(Yb, WpT, out, 4096, 1024, 1024, 1024);
}